// Round 1
// baseline (1650.024 us; speedup 1.0000x reference)
//
#include <hip/hip_runtime.h>
#include <stdint.h>

// Problem constants
#define LL 128
#define BB 4096
#define DD 300
#define DP 320              // K padded to multiple of 32
#define SROW 328            // LDS row stride in bf16 elements (bank advance = 4 dwords)

typedef __attribute__((ext_vector_type(8))) short short8;
typedef __attribute__((ext_vector_type(4))) float f32x4;

static constexpr int SMEM_BYTES = 129 * SROW * 2 + 256 * 4;  // S16 + q1s/q2s

__device__ __forceinline__ unsigned short f2bf(float f) {
    unsigned int u = __builtin_bit_cast(unsigned int, f);
    u = (u + 0x7fffu + ((u >> 16) & 1u)) >> 16;   // RNE
    return (unsigned short)u;
}
__device__ __forceinline__ float bf2f(unsigned short h) {
    unsigned int u = ((unsigned int)h) << 16;
    return __builtin_bit_cast(float, u);
}

// ---- prep: Wb[320][320] = bf16( 0.5*(W + W^T) ), zero padded ----
__global__ void prep_w_kernel(const float* __restrict__ W, unsigned short* __restrict__ Wb) {
    int i = blockIdx.x * 256 + threadIdx.x;
    if (i >= DP * DP) return;
    int r = i / DP, c = i % DP;
    float v = 0.0f;
    if (r < DD && c < DD) v = 0.5f * (W[r * DD + c] + W[c * DD + r]);
    Wb[i] = f2bf(v);
}

// ---- fused: scores via MFMA + softmax combine, one block per b ----
__global__ __launch_bounds__(512) void fused_kernel(
        const float* __restrict__ sent, const int* __restrict__ sizes,
        const unsigned short* __restrict__ Wb, float* __restrict__ out) {
    extern __shared__ char smem[];
    unsigned short* S16 = (unsigned short*)smem;
    float* q1s = (float*)(smem + 129 * SROW * 2);
    float* q2s = q1s + 128;

    const int b = blockIdx.x;
    const int t = threadIdx.x;

    // ---------------- stage sentence[:, b, :] as bf16 into LDS ----------------
    // 128 rows x 300 floats = 9600 float4 loads
    for (int idx = t; idx < 128 * 75; idx += 512) {
        int row = idx / 75, c4 = idx % 75;
        const float4 v = ((const float4*)(sent + ((size_t)row * BB + b) * DD))[c4];
        ushort4 h;
        h.x = f2bf(v.x); h.y = f2bf(v.y); h.z = f2bf(v.z); h.w = f2bf(v.w);
        *(ushort4*)&S16[row * SROW + c4 * 4] = h;
    }
    // zero pad cols 300..327 for all 129 rows
    for (int r = t; r < 129; r += 512) {
        #pragma unroll
        for (int c = 300; c < SROW; c += 4) {
            ushort4 z; z.x = 0; z.y = 0; z.z = 0; z.w = 0;
            *(ushort4*)&S16[r * SROW + c] = z;
        }
    }
    // zero row 128 (cols 0..299)
    for (int c4 = t; c4 < 75; c4 += 512) {
        ushort4 z; z.x = 0; z.y = 0; z.z = 0; z.w = 0;
        *(ushort4*)&S16[128 * SROW + c4 * 4] = z;
    }
    // zero score accumulators
    if (t < 256) q1s[t] = 0.0f;   // covers q1s[128] + q2s[128] (contiguous)
    __syncthreads();

    // ---------------- MFMA: Y = S * Wsym ; dots -> q1, q2 ----------------
    const int lane = t & 63;
    const int wave = t >> 6;       // 0..7
    const int mw = wave >> 2;      // 0..1  rows 64*mw
    const int nw = wave & 3;       // 0..3  cols 80*nw
    const int lo = lane & 15;
    const int quad = lane >> 4;

    f32x4 acc[4][5];
    #pragma unroll
    for (int m = 0; m < 4; m++)
        #pragma unroll
        for (int n = 0; n < 5; n++)
            acc[m][n] = (f32x4){0.f, 0.f, 0.f, 0.f};

    #pragma unroll
    for (int kc = 0; kc < 10; kc++) {
        short8 Af[4], Bf[5];
        #pragma unroll
        for (int m = 0; m < 4; m++)
            Af[m] = *(const short8*)&S16[(64 * mw + 16 * m + lo) * SROW + kc * 32 + quad * 8];
        #pragma unroll
        for (int n = 0; n < 5; n++)
            Bf[n] = *(const short8*)&Wb[(80 * nw + 16 * n + lo) * DP + kc * 32 + quad * 8];
        #pragma unroll
        for (int m = 0; m < 4; m++)
            #pragma unroll
            for (int n = 0; n < 5; n++)
                acc[m][n] = __builtin_amdgcn_mfma_f32_16x16x32_bf16(Af[m], Bf[n], acc[m][n], 0, 0, 0);
    }

    // dots: q1[row] += Y[row][col]*S[row][col]; q2[row] += Y[row][col]*S[row+1][col]
    float q1a[4][4], q2a[4][4];
    #pragma unroll
    for (int m = 0; m < 4; m++)
        #pragma unroll
        for (int r = 0; r < 4; r++) { q1a[m][r] = 0.f; q2a[m][r] = 0.f; }

    #pragma unroll
    for (int m = 0; m < 4; m++) {
        #pragma unroll
        for (int n = 0; n < 5; n++) {
            const int col = 80 * nw + 16 * n + lo;
            #pragma unroll
            for (int r = 0; r < 4; r++) {
                const int row = 64 * mw + 16 * m + quad * 4 + r;
                const float y = acc[m][n][r];
                q1a[m][r] += y * bf2f(S16[row * SROW + col]);
                q2a[m][r] += y * bf2f(S16[(row + 1) * SROW + col]);
            }
        }
    }

    // reduce across the 16 col-lanes, then atomicAdd across the 4 nw-waves
    #pragma unroll
    for (int m = 0; m < 4; m++) {
        #pragma unroll
        for (int r = 0; r < 4; r++) {
            float v1 = q1a[m][r], v2 = q2a[m][r];
            #pragma unroll
            for (int off = 1; off < 16; off <<= 1) {
                v1 += __shfl_xor(v1, off);
                v2 += __shfl_xor(v2, off);
            }
            if (lo == 0) {
                const int row = 64 * mw + 16 * m + quad * 4 + r;
                atomicAdd(&q1s[row], v1);
                atomicAdd(&q2s[row], v2);
            }
        }
    }
    __syncthreads();

    // ---------------- softmax + combine ----------------
    const int sz = sizes[b];
    const float inv_d = 1.0f / 300.0f;
    const float NEG_INF = -__builtin_inff();
    if (t < DD) {
        const int d = t;
        for (int l = 0; l < LL; l++) {
            const float a1 = q1s[l] * inv_d;
            const float a0 = (l >= 1 && l < sz) ? q2s[l - 1] * inv_d : NEG_INF;
            const float a2 = (l < LL - 1 && l < sz - 1) ? q2s[l] * inv_d : NEG_INF;
            const float mx = fmaxf(a1, fmaxf(a0, a2));
            const float e0 = __expf(a0 - mx);
            const float e1 = __expf(a1 - mx);
            const float e2 = __expf(a2 - mx);
            const float invsum = 1.0f / (e0 + e1 + e2);
            const int lp = (l == 0) ? 0 : (l - 1);           // weight 0 at l=0
            const float sp = bf2f(S16[lp * SROW + d]);
            const float sc = bf2f(S16[l * SROW + d]);
            const float sn = bf2f(S16[(l + 1) * SROW + d]);  // row 128 zeroed
            out[((size_t)l * BB + b) * DD + d] = (e1 * sc + e0 * sp + e2 * sn) * invsum;
        }
    }
}

extern "C" void kernel_launch(void* const* d_in, const int* in_sizes, int n_in,
                              void* d_out, int out_size, void* d_ws, size_t ws_size,
                              hipStream_t stream) {
    const float* sent = (const float*)d_in[0];
    const int* sizes  = (const int*)d_in[1];
    const float* W    = (const float*)d_in[2];
    float* out        = (float*)d_out;
    unsigned short* Wb = (unsigned short*)d_ws;   // 320*320*2 = 204800 B

    prep_w_kernel<<<(DP * DP + 255) / 256, 256, 0, stream>>>(W, Wb);

    hipFuncSetAttribute(reinterpret_cast<const void*>(fused_kernel),
                        hipFuncAttributeMaxDynamicSharedMemorySize, SMEM_BYTES);
    fused_kernel<<<BB, 512, SMEM_BYTES, stream>>>(sent, sizes, Wb, out);
}